// Round 1
// baseline (855.661 us; speedup 1.0000x reference)
//
#include <hip/hip_runtime.h>
#include <stdint.h>

#define BB 4
#define CC 128
#define HH 128
#define WW 128
#define LL 19
#define SS 512
#define HP 132
#define NPIX (HH*WW)      // 16384
#define PCELLS (HP*HP)    // 17424

typedef float f32x4 __attribute__((ext_vector_type(4)));
typedef __bf16 bf16x8 __attribute__((ext_vector_type(8)));
typedef short short8 __attribute__((ext_vector_type(8)));

__device__ inline unsigned short f2bf(float v){
  unsigned u = __float_as_uint(v);
  return (unsigned short)((u + 0x7fffu + ((u >> 16) & 1u)) >> 16);
}
__device__ inline float bflo(unsigned u){ return __uint_as_float(u << 16); }
__device__ inline float bfhi(unsigned u){ return __uint_as_float(u & 0xffff0000u); }

// ---------------- instance-norm stats: mean/rstd per (b,c) ----------------
__global__ void k_stats(const float* __restrict__ x, float* __restrict__ mean,
                        float* __restrict__ rstd){
  const int bc = blockIdx.x;
  const int t = threadIdx.x;
  const int w = t >> 6, lane = t & 63;
  const float4* xv = (const float4*)(x + (size_t)bc * NPIX);
  float s = 0.f, q = 0.f;
  for (int i = t; i < NPIX/4; i += 256){
    float4 v = xv[i];
    s += v.x + v.y + v.z + v.w;
    q += v.x*v.x + v.y*v.y + v.z*v.z + v.w*v.w;
  }
  #pragma unroll
  for (int off = 32; off; off >>= 1){ s += __shfl_down(s, off); q += __shfl_down(q, off); }
  __shared__ float ls[4], lq[4];
  if (lane == 0){ ls[w] = s; lq[w] = q; }
  __syncthreads();
  if (t == 0){
    float S = ls[0]+ls[1]+ls[2]+ls[3];
    float Q = lq[0]+lq[1]+lq[2]+lq[3];
    float mn = S * (1.f/16384.f);
    float var = Q * (1.f/16384.f) - mn*mn;
    mean[bc] = mn;
    rstd[bc] = rsqrtf(var + 1e-5f);
  }
}

// ---------------- padded label ids (border sentinel = 19) ----------------
__global__ void k_ids(const float* __restrict__ seg, int* __restrict__ ids){
  int idx = blockIdx.x*256 + threadIdx.x;
  if (idx >= BB*PCELLS) return;
  int b = idx / PCELLS; int rem = idx - b*PCELLS;
  int r = rem / HP;     int cp = rem - r*HP;
  int id = LL;  // sentinel: zero row in tables (== SAME zero padding)
  if (r >= 2 && r <= 129 && cp >= 2 && cp <= 129){
    int p = (r-2)*WW + (cp-2);
    const float* sp = seg + (size_t)b*LL*NPIX + p;
    id = 0;
    for (int j = 0; j < LL; ++j){
      if (sp[(size_t)j*NPIX] > 0.5f){ id = j; break; }
    }
  }
  ids[idx] = id;
}

// ---------------- per-(b,j) style FC: mu = relu(style @ fc_w^T + fc_b) ----
__global__ void k_fc(const float* __restrict__ style, const float* __restrict__ fcw,
                     const float* __restrict__ fcb, float* __restrict__ mu){
  const int blk = blockIdx.x;
  const int b = blk / LL, j = blk - b*LL;
  const int t = threadIdx.x;
  const int w = t >> 6, lane = t & 63;
  __shared__ float s_s[SS];
  s_s[t]       = style[(size_t)(b*LL + j)*SS + t];
  s_s[t + 256] = style[(size_t)(b*LL + j)*SS + t + 256];
  __syncthreads();
  for (int e = w; e < SS; e += 4){
    const float* row = fcw + ((size_t)(j*SS + e))*SS;
    float acc = 0.f;
    #pragma unroll
    for (int i = 0; i < 8; ++i){ int d = lane + i*64; acc += s_s[d] * row[d]; }
    #pragma unroll
    for (int off = 32; off; off >>= 1) acc += __shfl_down(acc, off);
    if (lane == 0) mu[(size_t)(b*LL + j)*SS + e] = fmaxf(acc + fcb[j*SS + e], 0.f);
  }
}

// ---------------- G table: G[b][c][j*25+d] = {gamma,beta} dot(mu, W) ------
__global__ void k_gtab(const float* __restrict__ mu, const float* __restrict__ wg,
                       const float* __restrict__ wb, float2* __restrict__ G){
  const int blk = blockIdx.x;
  const int b = blk >> 7, c = blk & 127;
  const int t = threadIdx.x;
  __shared__ float mu_s[LL*SS];
  for (int i = t; i < LL*SS; i += 256) mu_s[i] = mu[(size_t)b*LL*SS + i];
  __syncthreads();
  for (int idx = t; idx < 500; idx += 256){
    int j = idx / 25, d = idx - (idx/25)*25;
    float ag = 0.f, ab = 0.f;
    if (j < LL){
      const float* wgr = wg + (size_t)c*SS*25 + d;
      const float* wbr = wb + (size_t)c*SS*25 + d;
      const float* ms  = mu_s + j*SS;
      for (int e = 0; e < SS; ++e){
        float m = ms[e];
        ag += m * wgr[(size_t)e*25];
        ab += m * wbr[(size_t)e*25];
      }
    }
    G[((size_t)(b*CC + c))*500 + idx] = make_float2(ag, ab);
  }
}

// ---------------- shared-weight table Tt[j][d][s] (bf16, j=19 zeroed) -----
__global__ void k_ttab(const float* __restrict__ ssw, unsigned short* __restrict__ Tt){
  int idx = blockIdx.x*256 + threadIdx.x;
  if (idx >= 20*25*SS) return;
  int s = idx & 511; int rest = idx >> 9;
  int j = rest / 25, d = rest - (rest/25)*25;
  float v = 0.f;
  if (j < LL) v = ssw[((size_t)s*LL + j)*25 + d];
  Tt[idx] = f2bf(v);
}

// ---------------- spade conv weights -> W2[c'][tap*512+s] bf16 ------------
__global__ void k_w2(const float* __restrict__ wg, const float* __restrict__ wb,
                     unsigned short* __restrict__ W2){
  int idx = blockIdx.x*256 + threadIdx.x;
  if (idx >= 256*12800) return;
  int cpr = idx / 12800; int k = idx - cpr*12800;
  int tap = k >> 9; int s = k & 511;
  const float* w = (cpr < 128) ? wg : wb;
  int c = cpr & 127;
  W2[idx] = f2bf(w[((size_t)c*SS + s)*25 + tap]);
}

// ---------------- actv (NHWC bf16, zero-padded): relu(gather + bias) ------
__global__ void k_actv(const int* __restrict__ ids, const unsigned short* __restrict__ Tt,
                       const float* __restrict__ ssb, unsigned* __restrict__ actv){
  const int t = threadIdx.x;
  const int cell0 = blockIdx.x * 32;
  float bias0 = ssb[2*t], bias1 = ssb[2*t + 1];
  for (int i = 0; i < 32; ++i){
    int cell = cell0 + i;
    int b = cell / PCELLS; int rem = cell - b*PCELLS;
    int r = rem / HP;      int cp = rem - r*HP;
    unsigned outw = 0u;
    if (r >= 2 && r <= 129 && cp >= 2 && cp <= 129){
      float a0 = bias0, a1 = bias1;
      const int* idb = ids + b*PCELLS + (r-2)*HP + (cp-2);
      #pragma unroll
      for (int dy = 0; dy < 5; ++dy){
        #pragma unroll
        for (int dx = 0; dx < 5; ++dx){
          int id = idb[dy*HP + dx];  // wave-uniform -> scalar load
          unsigned u = *(const unsigned*)(Tt + ((size_t)(id*25 + dy*5 + dx))*SS + 2*t);
          a0 += bflo(u); a1 += bfhi(u);
        }
      }
      a0 = fmaxf(a0, 0.f); a1 = fmaxf(a1, 0.f);
      outw = (unsigned)f2bf(a0) | ((unsigned)f2bf(a1) << 16);
    }
    actv[(size_t)cell*256 + t] = outw;
  }
}

// ---------------- big conv: implicit GEMM, M=128 row-pixels, N=256, K=12800
__global__ __launch_bounds__(512, 2) void k_conv(
    const unsigned short* __restrict__ actv,   // bf16 [B][132][132][512]
    const unsigned short* __restrict__ W2,     // bf16 [256][12800]
    float* __restrict__ spade)                 // f32  [B][256][128][128]
{
  const int blk = blockIdx.x;
  const int b = blk >> 7, y = blk & 127;
  const int t = threadIdx.x;
  const int lane = t & 63;
  const int w = t >> 6;
  const int wr = w >> 2, wc = w & 3;
  __shared__ short As[128*32];   // [pixel][k]
  __shared__ short Bs[256*32];   // [n][k]
  f32x4 acc[4][4];
  #pragma unroll
  for (int m = 0; m < 4; ++m)
    #pragma unroll
    for (int n = 0; n < 4; ++n) acc[m][n] = (f32x4){0.f,0.f,0.f,0.f};

  const int pix = t >> 2, ch = t & 3;
  const size_t abase = (size_t)b * PCELLS * SS;

  auto loadA = [&](int kk) -> short8 {
    int tap = kk >> 4; int s0 = (kk & 15) << 5;
    int dy = tap / 5, dx = tap - dy*5;
    const unsigned short* p = actv + abase + ((size_t)((y+dy)*HP + (pix+dx)))*SS + s0 + ch*8;
    return *(const short8*)p;
  };
  auto loadB = [&](int kk, int h) -> short8 {
    int n = h*128 + pix;
    const unsigned short* p = W2 + (size_t)n*12800 + kk*32 + ch*8;
    return *(const short8*)p;
  };

  short8 ra = loadA(0), rb0 = loadB(0,0), rb1 = loadB(0,1);
  for (int kk = 0; kk < 400; ++kk){
    __syncthreads();
    *(short8*)&As[t*8] = ra;
    *(short8*)&Bs[t*8] = rb0;
    *(short8*)&Bs[4096 + t*8] = rb1;
    __syncthreads();
    if (kk < 399){ ra = loadA(kk+1); rb0 = loadB(kk+1,0); rb1 = loadB(kk+1,1); }
    bf16x8 af[4], bfr[4];
    #pragma unroll
    for (int m = 0; m < 4; ++m)
      af[m] = *reinterpret_cast<const bf16x8*>(&As[(wr*64 + m*16 + (lane&15))*32 + (lane>>4)*8]);
    #pragma unroll
    for (int n = 0; n < 4; ++n)
      bfr[n] = *reinterpret_cast<const bf16x8*>(&Bs[(wc*64 + n*16 + (lane&15))*32 + (lane>>4)*8]);
    #pragma unroll
    for (int m = 0; m < 4; ++m)
      #pragma unroll
      for (int n = 0; n < 4; ++n)
        acc[m][n] = __builtin_amdgcn_mfma_f32_16x16x32_bf16(af[m], bfr[n], acc[m][n], 0, 0, 0);
  }
  // epilogue: D col = lane&15 -> c', D row = (lane>>4)*4+reg -> pixel x (contig -> float4)
  const int xq = wr*64 + ((lane >> 4) << 2);
  const int cq = wc*64 + (lane & 15);
  #pragma unroll
  for (int m = 0; m < 4; ++m){
    #pragma unroll
    for (int n = 0; n < 4; ++n){
      int cp = cq + n*16;
      int x  = xq + m*16;
      float* p = spade + ((size_t)(b*256 + cp)*HH + y)*WW + x;
      *(f32x4*)p = acc[m][n];
    }
  }
}

// ---------------- final: avg-path gather + blend + instance-norm apply ----
__global__ void k_final(const float* __restrict__ xin, const int* __restrict__ ids,
                        const float2* __restrict__ G, const float* __restrict__ spade,
                        const float* __restrict__ mean, const float* __restrict__ rstd,
                        const float* __restrict__ cgb, const float* __restrict__ cbb,
                        const float* __restrict__ sgb, const float* __restrict__ sbb,
                        const float* __restrict__ bgam, const float* __restrict__ bbet,
                        float* __restrict__ out){
  const int blk = blockIdx.x;
  const int b = blk >> 7, c = blk & 127;
  const int t = threadIdx.x;
  __shared__ float2 Gl[500];
  for (int i = t; i < 500; i += 256) Gl[i] = G[((size_t)(b*CC + c))*500 + i];
  __syncthreads();
  const float ga = 1.f/(1.f + __expf(-bgam[0]));
  const float ba = 1.f/(1.f + __expf(-bbet[0]));
  const float mn = mean[b*CC + c], rs = rstd[b*CC + c];
  const float cg = cgb[c], cb = cbb[c], sg = sgb[c], sb = sbb[c];
  const float* xp  = xin   + (size_t)(b*CC + c)*NPIX;
  const float* spg = spade + (size_t)(b*256 + c)*NPIX;
  const float* spb = spade + (size_t)(b*256 + c + 128)*NPIX;
  float* op = out + (size_t)(b*CC + c)*NPIX;
  const int* idb = ids + b*PCELLS;
  for (int p = t; p < NPIX; p += 256){
    int y = p >> 7, x = p & 127;
    float ag = 0.f, ab = 0.f;
    #pragma unroll
    for (int dy = 0; dy < 5; ++dy){
      const int* row = idb + (y+dy)*HP + x;
      #pragma unroll
      for (int dx = 0; dx < 5; ++dx){
        int id = row[dx];
        float2 g2 = Gl[id*25 + dy*5 + dx];
        ag += g2.x; ab += g2.y;
      }
    }
    float gf = ga*(ag + cg) + (1.f - ga)*(spg[p] + sg);
    float bf = ba*(ab + cb) + (1.f - ba)*(spb[p] + sb);
    op[p] = (xp[p] - mn)*rs*(1.f + gf) + bf;
  }
}

extern "C" void kernel_launch(void* const* d_in, const int* in_sizes, int n_in,
                              void* d_out, int out_size, void* d_ws, size_t ws_size,
                              hipStream_t stream){
  const float* x    = (const float*)d_in[0];
  const float* seg  = (const float*)d_in[1];
  const float* sty  = (const float*)d_in[2];
  const float* fcw  = (const float*)d_in[3];
  const float* fcb  = (const float*)d_in[4];
  const float* cgw  = (const float*)d_in[5];
  const float* cgb  = (const float*)d_in[6];
  const float* cbw  = (const float*)d_in[7];
  const float* cbb  = (const float*)d_in[8];
  const float* ssw  = (const float*)d_in[9];
  const float* ssb  = (const float*)d_in[10];
  const float* sgw  = (const float*)d_in[11];
  const float* sgb  = (const float*)d_in[12];
  const float* sbw  = (const float*)d_in[13];
  const float* sbb  = (const float*)d_in[14];
  const float* bgam = (const float*)d_in[15];
  const float* bbet = (const float*)d_in[16];
  float* out = (float*)d_out;

  char* ws = (char*)d_ws;
  size_t o = 0;
  auto alloc = [&](size_t n){ size_t r = o; o = (o + n + 255) & ~(size_t)255; return r; };
  float* mean          = (float*)(ws + alloc(512*4));
  float* rstd          = (float*)(ws + alloc(512*4));
  int*   ids           = (int*)  (ws + alloc((size_t)BB*PCELLS*4));
  float* mu            = (float*)(ws + alloc((size_t)BB*LL*SS*4));
  float2* G            = (float2*)(ws + alloc((size_t)BB*CC*500*8));
  unsigned short* Tt   = (unsigned short*)(ws + alloc((size_t)20*25*SS*2));
  unsigned short* W2   = (unsigned short*)(ws + alloc((size_t)256*12800*2));
  unsigned short* actv = (unsigned short*)(ws + alloc((size_t)BB*PCELLS*SS*2));
  float* spade         = (float*)(ws + alloc((size_t)BB*256*NPIX*4));
  (void)o; (void)ws_size; (void)in_sizes; (void)n_in; (void)out_size; (void)sty;

  k_stats<<<dim3(512),  dim3(256), 0, stream>>>(x, mean, rstd);
  k_ids  <<<dim3(273),  dim3(256), 0, stream>>>(seg, ids);
  k_fc   <<<dim3(76),   dim3(256), 0, stream>>>(sty, fcw, fcb, mu);
  k_gtab <<<dim3(512),  dim3(256), 0, stream>>>(mu, cgw, cbw, G);
  k_ttab <<<dim3(1000), dim3(256), 0, stream>>>(ssw, Tt);
  k_w2   <<<dim3(12800),dim3(256), 0, stream>>>(sgw, sbw, W2);
  k_actv <<<dim3(2178), dim3(256), 0, stream>>>(ids, Tt, ssb, (unsigned*)actv);
  k_conv <<<dim3(512),  dim3(512), 0, stream>>>(actv, W2, spade);
  k_final<<<dim3(512),  dim3(256), 0, stream>>>(x, ids, G, spade, mean, rstd,
                                                cgb, cbb, sgb, sbb, bgam, bbet, out);
}

// Round 2
// 774.059 us; speedup vs baseline: 1.1054x; 1.1054x over previous
//
#include <hip/hip_runtime.h>
#include <stdint.h>

#define BB 4
#define CC 128
#define HH 128
#define WW 128
#define LL 19
#define SS 512
#define HP 132
#define NPIX (HH*WW)      // 16384
#define PCELLS (HP*HP)    // 17424

typedef float f32x4 __attribute__((ext_vector_type(4)));
typedef __bf16 bf16x8 __attribute__((ext_vector_type(8)));
typedef short short8 __attribute__((ext_vector_type(8)));

#define AS1Q __attribute__((address_space(1)))
#define AS3Q __attribute__((address_space(3)))
#define MEMFENCE asm volatile("" ::: "memory")

__device__ __forceinline__ void gld16(const void* g, void* l){
  __builtin_amdgcn_global_load_lds((const AS1Q void*)g, (AS3Q void*)l, 16, 0, 0);
}

__device__ inline unsigned short f2bf(float v){
  unsigned u = __float_as_uint(v);
  return (unsigned short)((u + 0x7fffu + ((u >> 16) & 1u)) >> 16);
}
__device__ inline float bflo(unsigned u){ return __uint_as_float(u << 16); }
__device__ inline float bfhi(unsigned u){ return __uint_as_float(u & 0xffff0000u); }

// ---------------- instance-norm stats: mean/rstd per (b,c) ----------------
__global__ void k_stats(const float* __restrict__ x, float* __restrict__ mean,
                        float* __restrict__ rstd){
  const int bc = blockIdx.x;
  const int t = threadIdx.x;
  const int w = t >> 6, lane = t & 63;
  const float4* xv = (const float4*)(x + (size_t)bc * NPIX);
  float s = 0.f, q = 0.f;
  for (int i = t; i < NPIX/4; i += 256){
    float4 v = xv[i];
    s += v.x + v.y + v.z + v.w;
    q += v.x*v.x + v.y*v.y + v.z*v.z + v.w*v.w;
  }
  #pragma unroll
  for (int off = 32; off; off >>= 1){ s += __shfl_down(s, off); q += __shfl_down(q, off); }
  __shared__ float ls[4], lq[4];
  if (lane == 0){ ls[w] = s; lq[w] = q; }
  __syncthreads();
  if (t == 0){
    float S = ls[0]+ls[1]+ls[2]+ls[3];
    float Q = lq[0]+lq[1]+lq[2]+lq[3];
    float mn = S * (1.f/16384.f);
    float var = Q * (1.f/16384.f) - mn*mn;
    mean[bc] = mn;
    rstd[bc] = rsqrtf(var + 1e-5f);
  }
}

// ---------------- padded label ids (border sentinel = 19) ----------------
__global__ void k_ids(const float* __restrict__ seg, int* __restrict__ ids){
  int idx = blockIdx.x*256 + threadIdx.x;
  if (idx >= BB*PCELLS) return;
  int b = idx / PCELLS; int rem = idx - b*PCELLS;
  int r = rem / HP;     int cp = rem - r*HP;
  int id = LL;  // sentinel: zero row in tables (== SAME zero padding)
  if (r >= 2 && r <= 129 && cp >= 2 && cp <= 129){
    int p = (r-2)*WW + (cp-2);
    const float* sp = seg + (size_t)b*LL*NPIX + p;
    id = 0;
    for (int j = 0; j < LL; ++j){
      if (sp[(size_t)j*NPIX] > 0.5f){ id = j; break; }
    }
  }
  ids[idx] = id;
}

// ---------------- per-(b,j) style FC: mu = relu(style @ fc_w^T + fc_b) ----
__global__ void k_fc(const float* __restrict__ style, const float* __restrict__ fcw,
                     const float* __restrict__ fcb, float* __restrict__ mu){
  const int blk = blockIdx.x;
  const int b = blk / LL, j = blk - b*LL;
  const int t = threadIdx.x;
  const int w = t >> 6, lane = t & 63;
  __shared__ float s_s[SS];
  s_s[t]       = style[(size_t)(b*LL + j)*SS + t];
  s_s[t + 256] = style[(size_t)(b*LL + j)*SS + t + 256];
  __syncthreads();
  for (int e = w; e < SS; e += 4){
    const float* row = fcw + ((size_t)(j*SS + e))*SS;
    float acc = 0.f;
    #pragma unroll
    for (int i = 0; i < 8; ++i){ int d = lane + i*64; acc += s_s[d] * row[d]; }
    #pragma unroll
    for (int off = 32; off; off >>= 1) acc += __shfl_down(acc, off);
    if (lane == 0) mu[(size_t)(b*LL + j)*SS + e] = fmaxf(acc + fcb[j*SS + e], 0.f);
  }
}

// ---------------- G table: G[b][c][j*25+d] = {gamma,beta} dot(mu, W) ------
__global__ void k_gtab(const float* __restrict__ mu, const float* __restrict__ wg,
                       const float* __restrict__ wb, float2* __restrict__ G){
  const int blk = blockIdx.x;
  const int b = blk >> 7, c = blk & 127;
  const int t = threadIdx.x;
  __shared__ float mu_s[LL*SS];
  for (int i = t; i < LL*SS; i += 256) mu_s[i] = mu[(size_t)b*LL*SS + i];
  __syncthreads();
  for (int idx = t; idx < 500; idx += 256){
    int j = idx / 25, d = idx - (idx/25)*25;
    float ag = 0.f, ab = 0.f;
    if (j < LL){
      const float* wgr = wg + (size_t)c*SS*25 + d;
      const float* wbr = wb + (size_t)c*SS*25 + d;
      const float* ms  = mu_s + j*SS;
      for (int e = 0; e < SS; ++e){
        float m = ms[e];
        ag += m * wgr[(size_t)e*25];
        ab += m * wbr[(size_t)e*25];
      }
    }
    G[((size_t)(b*CC + c))*500 + idx] = make_float2(ag, ab);
  }
}

// ---------------- shared-weight table Tt[j][d][s] (bf16, j=19 zeroed) -----
__global__ void k_ttab(const float* __restrict__ ssw, unsigned short* __restrict__ Tt){
  int idx = blockIdx.x*256 + threadIdx.x;
  if (idx >= 20*25*SS) return;
  int s = idx & 511; int rest = idx >> 9;
  int j = rest / 25, d = rest - (rest/25)*25;
  float v = 0.f;
  if (j < LL) v = ssw[((size_t)s*LL + j)*25 + d];
  Tt[idx] = f2bf(v);
}

// ---------------- spade conv weights -> W2[c'][tap*512+s] bf16 ------------
__global__ void k_w2(const float* __restrict__ wg, const float* __restrict__ wb,
                     unsigned short* __restrict__ W2){
  int idx = blockIdx.x*256 + threadIdx.x;
  if (idx >= 256*12800) return;
  int cpr = idx / 12800; int k = idx - cpr*12800;
  int tap = k >> 9; int s = k & 511;
  const float* w = (cpr < 128) ? wg : wb;
  int c = cpr & 127;
  W2[idx] = f2bf(w[((size_t)c*SS + s)*25 + tap]);
}

// ---------------- actv (NHWC bf16, zero-padded): relu(gather + bias) ------
__global__ void k_actv(const int* __restrict__ ids, const unsigned short* __restrict__ Tt,
                       const float* __restrict__ ssb, unsigned* __restrict__ actv){
  const int t = threadIdx.x;
  const int cell0 = blockIdx.x * 32;
  float bias0 = ssb[2*t], bias1 = ssb[2*t + 1];
  for (int i = 0; i < 32; ++i){
    int cell = cell0 + i;
    int b = cell / PCELLS; int rem = cell - b*PCELLS;
    int r = rem / HP;      int cp = rem - r*HP;
    unsigned outw = 0u;
    if (r >= 2 && r <= 129 && cp >= 2 && cp <= 129){
      float a0 = bias0, a1 = bias1;
      const int* idb = ids + b*PCELLS + (r-2)*HP + (cp-2);
      #pragma unroll
      for (int dy = 0; dy < 5; ++dy){
        #pragma unroll
        for (int dx = 0; dx < 5; ++dx){
          int id = idb[dy*HP + dx];  // block-uniform -> broadcast
          unsigned u = *(const unsigned*)(Tt + ((size_t)(id*25 + dy*5 + dx))*SS + 2*t);
          a0 += bflo(u); a1 += bfhi(u);
        }
      }
      a0 = fmaxf(a0, 0.f); a1 = fmaxf(a1, 0.f);
      outw = (unsigned)f2bf(a0) | ((unsigned)f2bf(a1) << 16);
    }
    actv[(size_t)cell*256 + t] = outw;
  }
}

// ---------------- big conv: implicit GEMM, M=256 pixels (2 rows), N=256 ---
// BK=32, 4 LDS buffers, stage-ahead=3 via global_load_lds(16B), counted
// vmcnt(12), XOR-swizzled LDS reads (source-swizzled per rule 21).
__global__ __launch_bounds__(512, 2) void k_conv(
    const unsigned short* __restrict__ actv,   // bf16 [B][132][132][512]
    const unsigned short* __restrict__ W2,     // bf16 [256][12800]
    float* __restrict__ spade)                 // f32  [B][256][128][128]
{
  __shared__ int4 lds4[131072/16];             // 128 KiB: 4 bufs x (A 16K + B 16K)
  char* ldsb = (char*)lds4;
  const int blk = blockIdx.x;
  const int b  = blk >> 6;
  const int y0 = (blk & 63) * 2;
  const int t  = threadIdx.x;
  const int lane = t & 63;
  const int w  = t >> 6;
  const int wr = w >> 2, wc = w & 3;
  const int li = lane & 15, q = lane >> 4;

  // ---- staging constants (per thread): source pre-swizzle (rule 21) ----
  const int lsub  = lane >> 2;                           // 0..15
  const int s_src = (lane & 3) ^ ((lane >> 3) & 3);      // swizzled k-slot
  const bool isA  = (w < 4);
  const char* p0[4];
  int ldsrel[4];
  #pragma unroll
  for (int l = 0; l < 4; ++l){
    int row = (isA ? w : (w - 4)) * 64 + l*16 + lsub;    // pixel r or channel n
    if (isA){
      int y = y0 + (row >> 7), x = row & 127;
      p0[l] = (const char*)(actv + (((size_t)b*HP + y)*HP + x)*SS + s_src*8);
    } else {
      p0[l] = (const char*)(W2 + (size_t)row*12800 + s_src*8);
    }
    ldsrel[l] = w*4096 + l*1024 + lane*16;
  }

  auto stage = [&](int tt){
    size_t offA;
    {
      int tap = tt >> 4;
      int dy = tap / 5, dx = tap - dy*5;
      offA = ((size_t)(dy*HP + dx)*SS + (size_t)(tt & 15)*32) * 2;
    }
    size_t off = isA ? offA : (size_t)tt * 64;
    char* base = ldsb + ((tt & 3) * 32768);
    #pragma unroll
    for (int l = 0; l < 4; ++l)
      gld16(p0[l] + off, base + ldsrel[l]);
  };

  f32x4 acc[8][4];
  #pragma unroll
  for (int m = 0; m < 8; ++m)
    #pragma unroll
    for (int n = 0; n < 4; ++n) acc[m][n] = (f32x4){0.f,0.f,0.f,0.f};

  const int swz = (q ^ ((li >> 1) & 3)) * 16;            // read-side swizzle

  auto body = [&](int tt){
    const char* buf = ldsb + (tt & 3) * 32768;
    const char* arow = buf + (wr*128 + li)*64 + swz;
    const char* brow = buf + 16384 + (wc*64 + li)*64 + swz;
    bf16x8 af[8], bfv[4];
    #pragma unroll
    for (int m = 0; m < 8; ++m) af[m] = *(const bf16x8*)(arow + m*1024);
    #pragma unroll
    for (int n = 0; n < 4; ++n) bfv[n] = *(const bf16x8*)(brow + n*1024);
    __builtin_amdgcn_s_setprio(1);
    #pragma unroll
    for (int m = 0; m < 8; ++m)
      #pragma unroll
      for (int n = 0; n < 4; ++n)
        acc[m][n] = __builtin_amdgcn_mfma_f32_16x16x32_bf16(af[m], bfv[n], acc[m][n], 0, 0, 0);
    __builtin_amdgcn_s_setprio(0);
  };

  // prologue: 3 tiles in flight
  stage(0); stage(1); stage(2);
  for (int tt = 0; tt < 397; ++tt){
    stage(tt + 3);
    asm volatile("s_waitcnt vmcnt(12)" ::: "memory");
    __builtin_amdgcn_s_barrier();
    MEMFENCE;
    body(tt);
    MEMFENCE;
    __builtin_amdgcn_s_barrier();
    MEMFENCE;
  }
  asm volatile("s_waitcnt vmcnt(8)" ::: "memory");
  __builtin_amdgcn_s_barrier();
  MEMFENCE;
  body(397);
  MEMFENCE;
  __builtin_amdgcn_s_barrier();
  MEMFENCE;
  asm volatile("s_waitcnt vmcnt(4)" ::: "memory");
  __builtin_amdgcn_s_barrier();
  MEMFENCE;
  body(398);
  MEMFENCE;
  __builtin_amdgcn_s_barrier();
  MEMFENCE;
  asm volatile("s_waitcnt vmcnt(0)" ::: "memory");
  __builtin_amdgcn_s_barrier();
  MEMFENCE;
  body(399);

  // epilogue: D col = lane&15 -> c', D row = (lane>>4)*4+reg -> pixel
  const int xq4 = (lane >> 4) << 2;
  const int cq  = wc*64 + (lane & 15);
  #pragma unroll
  for (int m = 0; m < 8; ++m){
    int p = wr*128 + m*16 + xq4;
    int y = y0 + (p >> 7), x = p & 127;
    #pragma unroll
    for (int n = 0; n < 4; ++n){
      int cp = cq + n*16;
      float* dst = spade + (((size_t)(b*256 + cp))*HH + y)*WW + x;
      *(f32x4*)dst = acc[m][n];
    }
  }
}

// ---------------- final: avg-path gather + blend + instance-norm apply ----
__global__ void k_final(const float* __restrict__ xin, const int* __restrict__ ids,
                        const float2* __restrict__ G, const float* __restrict__ spade,
                        const float* __restrict__ mean, const float* __restrict__ rstd,
                        const float* __restrict__ cgb, const float* __restrict__ cbb,
                        const float* __restrict__ sgb, const float* __restrict__ sbb,
                        const float* __restrict__ bgam, const float* __restrict__ bbet,
                        float* __restrict__ out){
  const int blk = blockIdx.x;
  const int b = blk >> 7, c = blk & 127;
  const int t = threadIdx.x;
  __shared__ float2 Gl[500];
  for (int i = t; i < 500; i += 256) Gl[i] = G[((size_t)(b*CC + c))*500 + i];
  __syncthreads();
  const float ga = 1.f/(1.f + __expf(-bgam[0]));
  const float ba = 1.f/(1.f + __expf(-bbet[0]));
  const float mn = mean[b*CC + c], rs = rstd[b*CC + c];
  const float cg = cgb[c], cb = cbb[c], sg = sgb[c], sb = sbb[c];
  const float* xp  = xin   + (size_t)(b*CC + c)*NPIX;
  const float* spg = spade + (size_t)(b*256 + c)*NPIX;
  const float* spb = spade + (size_t)(b*256 + c + 128)*NPIX;
  float* op = out + (size_t)(b*CC + c)*NPIX;
  const int* idb = ids + b*PCELLS;
  for (int p = t; p < NPIX; p += 256){
    int y = p >> 7, x = p & 127;
    float ag = 0.f, ab = 0.f;
    #pragma unroll
    for (int dy = 0; dy < 5; ++dy){
      const int* row = idb + (y+dy)*HP + x;
      #pragma unroll
      for (int dx = 0; dx < 5; ++dx){
        int id = row[dx];
        float2 g2 = Gl[id*25 + dy*5 + dx];
        ag += g2.x; ab += g2.y;
      }
    }
    float gf = ga*(ag + cg) + (1.f - ga)*(spg[p] + sg);
    float bf = ba*(ab + cb) + (1.f - ba)*(spb[p] + sb);
    op[p] = (xp[p] - mn)*rs*(1.f + gf) + bf;
  }
}

extern "C" void kernel_launch(void* const* d_in, const int* in_sizes, int n_in,
                              void* d_out, int out_size, void* d_ws, size_t ws_size,
                              hipStream_t stream){
  const float* x    = (const float*)d_in[0];
  const float* seg  = (const float*)d_in[1];
  const float* sty  = (const float*)d_in[2];
  const float* fcw  = (const float*)d_in[3];
  const float* fcb  = (const float*)d_in[4];
  const float* cgw  = (const float*)d_in[5];
  const float* cgb  = (const float*)d_in[6];
  const float* cbw  = (const float*)d_in[7];
  const float* cbb  = (const float*)d_in[8];
  const float* ssw  = (const float*)d_in[9];
  const float* ssb  = (const float*)d_in[10];
  const float* sgw  = (const float*)d_in[11];
  const float* sgb  = (const float*)d_in[12];
  const float* sbw  = (const float*)d_in[13];
  const float* sbb  = (const float*)d_in[14];
  const float* bgam = (const float*)d_in[15];
  const float* bbet = (const float*)d_in[16];
  float* out = (float*)d_out;

  char* ws = (char*)d_ws;
  size_t o = 0;
  auto alloc = [&](size_t n){ size_t r = o; o = (o + n + 255) & ~(size_t)255; return r; };
  float* mean          = (float*)(ws + alloc(512*4));
  float* rstd          = (float*)(ws + alloc(512*4));
  int*   ids           = (int*)  (ws + alloc((size_t)BB*PCELLS*4));
  float* mu            = (float*)(ws + alloc((size_t)BB*LL*SS*4));
  float2* G            = (float2*)(ws + alloc((size_t)BB*CC*500*8));
  unsigned short* Tt   = (unsigned short*)(ws + alloc((size_t)20*25*SS*2));
  unsigned short* W2   = (unsigned short*)(ws + alloc((size_t)256*12800*2));
  unsigned short* actv = (unsigned short*)(ws + alloc((size_t)BB*PCELLS*SS*2));
  float* spade         = (float*)(ws + alloc((size_t)BB*256*NPIX*4));
  (void)o; (void)ws_size; (void)in_sizes; (void)n_in; (void)out_size; (void)sty;

  k_stats<<<dim3(512),  dim3(256), 0, stream>>>(x, mean, rstd);
  k_ids  <<<dim3(273),  dim3(256), 0, stream>>>(seg, ids);
  k_fc   <<<dim3(76),   dim3(256), 0, stream>>>(sty, fcw, fcb, mu);
  k_gtab <<<dim3(512),  dim3(256), 0, stream>>>(mu, cgw, cbw, G);
  k_ttab <<<dim3(1000), dim3(256), 0, stream>>>(ssw, Tt);
  k_w2   <<<dim3(12800),dim3(256), 0, stream>>>(sgw, sbw, W2);
  k_actv <<<dim3(2178), dim3(256), 0, stream>>>(ids, Tt, ssb, (unsigned*)actv);
  k_conv <<<dim3(256),  dim3(512), 0, stream>>>(actv, W2, spade);
  k_final<<<dim3(512),  dim3(256), 0, stream>>>(x, ids, G, spade, mean, rstd,
                                                cgb, cbb, sgb, sbb, bgam, bbet, out);
}

// Round 3
// 755.889 us; speedup vs baseline: 1.1320x; 1.0240x over previous
//
#include <hip/hip_runtime.h>
#include <stdint.h>

#define BB 4
#define CC 128
#define HH 128
#define WW 128
#define LL 19
#define SS 512
#define HP 132
#define NPIX (HH*WW)      // 16384
#define PCELLS (HP*HP)    // 17424

typedef float f32x4 __attribute__((ext_vector_type(4)));
typedef __bf16 bf16x8 __attribute__((ext_vector_type(8)));
typedef short short8 __attribute__((ext_vector_type(8)));

#define AS1Q __attribute__((address_space(1)))
#define AS3Q __attribute__((address_space(3)))
#define MEMFENCE asm volatile("" ::: "memory")

__device__ __forceinline__ void gld16(const void* g, void* l){
  __builtin_amdgcn_global_load_lds((const AS1Q void*)g, (AS3Q void*)l, 16, 0, 0);
}

__device__ inline unsigned short f2bf(float v){
  unsigned u = __float_as_uint(v);
  return (unsigned short)((u + 0x7fffu + ((u >> 16) & 1u)) >> 16);
}
__device__ inline float bflo(unsigned u){ return __uint_as_float(u << 16); }
__device__ inline float bfhi(unsigned u){ return __uint_as_float(u & 0xffff0000u); }

// ---------------- instance-norm stats: mean/rstd per (b,c) ----------------
__global__ void k_stats(const float* __restrict__ x, float* __restrict__ mean,
                        float* __restrict__ rstd){
  const int bc = blockIdx.x;
  const int t = threadIdx.x;
  const int w = t >> 6, lane = t & 63;
  const float4* xv = (const float4*)(x + (size_t)bc * NPIX);
  float s = 0.f, q = 0.f;
  for (int i = t; i < NPIX/4; i += 256){
    float4 v = xv[i];
    s += v.x + v.y + v.z + v.w;
    q += v.x*v.x + v.y*v.y + v.z*v.z + v.w*v.w;
  }
  #pragma unroll
  for (int off = 32; off; off >>= 1){ s += __shfl_down(s, off); q += __shfl_down(q, off); }
  __shared__ float ls[4], lq[4];
  if (lane == 0){ ls[w] = s; lq[w] = q; }
  __syncthreads();
  if (t == 0){
    float S = ls[0]+ls[1]+ls[2]+ls[3];
    float Q = lq[0]+lq[1]+lq[2]+lq[3];
    float mn = S * (1.f/16384.f);
    float var = Q * (1.f/16384.f) - mn*mn;
    mean[bc] = mn;
    rstd[bc] = rsqrtf(var + 1e-5f);
  }
}

// ---------------- padded label ids (border sentinel = 19) ----------------
__global__ void k_ids(const float* __restrict__ seg, int* __restrict__ ids){
  int idx = blockIdx.x*256 + threadIdx.x;
  if (idx >= BB*PCELLS) return;
  int b = idx / PCELLS; int rem = idx - b*PCELLS;
  int r = rem / HP;     int cp = rem - r*HP;
  int id = LL;  // sentinel: zero row in tables (== SAME zero padding)
  if (r >= 2 && r <= 129 && cp >= 2 && cp <= 129){
    int p = (r-2)*WW + (cp-2);
    const float* sp = seg + (size_t)b*LL*NPIX + p;
    id = 0;
    for (int j = 0; j < LL; ++j){
      if (sp[(size_t)j*NPIX] > 0.5f){ id = j; break; }
    }
  }
  ids[idx] = id;
}

// ---------------- per-(b,j) style FC: mu = relu(style @ fc_w^T + fc_b) ----
__global__ void k_fc(const float* __restrict__ style, const float* __restrict__ fcw,
                     const float* __restrict__ fcb, float* __restrict__ mu){
  const int blk = blockIdx.x;
  const int b = blk / LL, j = blk - b*LL;
  const int t = threadIdx.x;
  const int w = t >> 6, lane = t & 63;
  __shared__ float s_s[SS];
  s_s[t]       = style[(size_t)(b*LL + j)*SS + t];
  s_s[t + 256] = style[(size_t)(b*LL + j)*SS + t + 256];
  __syncthreads();
  for (int e = w; e < SS; e += 4){
    const float* row = fcw + ((size_t)(j*SS + e))*SS;
    float acc = 0.f;
    #pragma unroll
    for (int i = 0; i < 8; ++i){ int d = lane + i*64; acc += s_s[d] * row[d]; }
    #pragma unroll
    for (int off = 32; off; off >>= 1) acc += __shfl_down(acc, off);
    if (lane == 0) mu[(size_t)(b*LL + j)*SS + e] = fmaxf(acc + fcb[j*SS + e], 0.f);
  }
}

// ---------------- transpose conv_gamma/beta weights: Wt[c][d][e] f32 ------
__global__ void k_w2t(const float* __restrict__ wg, const float* __restrict__ wb,
                      float* __restrict__ Wtg, float* __restrict__ Wtb){
  int idx = blockIdx.x*256 + threadIdx.x;   // over 128*25*512
  if (idx >= 128*25*512) return;
  int e = idx & 511; int rest = idx >> 9;   // rest = c*25+d
  int c = rest / 25, d = rest - (rest/25)*25;
  size_t src = ((size_t)c*SS + e)*25 + d;
  Wtg[idx] = wg[src];
  Wtb[idx] = wb[src];
}

// ---------------- G table: wave-per-output coalesced dot ------------------
__global__ void k_gtab(const float* __restrict__ mu, const float* __restrict__ Wtg,
                       const float* __restrict__ Wtb, float2* __restrict__ G){
  const int blk = blockIdx.x;
  const int b = blk >> 7, c = blk & 127;
  const int t = threadIdx.x, w = t >> 6, lane = t & 63;
  __shared__ float mu_s[LL*SS];
  for (int i = t; i < LL*SS; i += 256) mu_s[i] = mu[(size_t)b*LL*SS + i];
  __syncthreads();
  for (int i = 0; i < 125; ++i){
    int o = i*4 + w;               // 0..499
    int j = o / 25, d = o - (o/25)*25;
    float ag = 0.f, ab = 0.f;
    if (j < LL){
      const float4* wg4 = (const float4*)(Wtg + ((size_t)c*25 + d)*SS);
      const float4* wb4 = (const float4*)(Wtb + ((size_t)c*25 + d)*SS);
      const float4* m4p = (const float4*)(mu_s + j*SS);
      #pragma unroll
      for (int rp = 0; rp < 2; ++rp){
        int e4 = rp*64 + lane;
        float4 m4 = m4p[e4];
        float4 wv = wg4[e4];
        ag += m4.x*wv.x + m4.y*wv.y + m4.z*wv.z + m4.w*wv.w;
        float4 wv2 = wb4[e4];
        ab += m4.x*wv2.x + m4.y*wv2.y + m4.z*wv2.z + m4.w*wv2.w;
      }
      #pragma unroll
      for (int off = 32; off; off >>= 1){ ag += __shfl_down(ag, off); ab += __shfl_down(ab, off); }
    }
    if (lane == 0) G[((size_t)(b*CC + c))*500 + o] = make_float2(ag, ab);
  }
}

// ---------------- shared-weight table Tt[j][d][s] (bf16, j=19 zeroed) -----
__global__ void k_ttab(const float* __restrict__ ssw, unsigned short* __restrict__ Tt){
  int idx = blockIdx.x*256 + threadIdx.x;
  if (idx >= 20*25*SS) return;
  int s = idx & 511; int rest = idx >> 9;
  int j = rest / 25, d = rest - (rest/25)*25;
  float v = 0.f;
  if (j < LL) v = ssw[((size_t)s*LL + j)*25 + d];
  Tt[idx] = f2bf(v);
}

// ---------------- spade conv weights -> W2[c'][k], k-order: s-chunk major -
// k = schunk*800 + tap*32 + s_in ;  s = schunk*32 + s_in
__global__ void k_w2(const float* __restrict__ wg, const float* __restrict__ wb,
                     unsigned short* __restrict__ W2){
  int idx = blockIdx.x*256 + threadIdx.x;
  if (idx >= 256*12800) return;
  int cpr = idx / 12800; int k = idx - cpr*12800;
  int schunk = k / 800; int r800 = k - schunk*800;
  int tap = r800 >> 5;  int s_in = r800 & 31;
  int s = schunk*32 + s_in;
  const float* w = (cpr < 128) ? wg : wb;
  int c = cpr & 127;
  W2[idx] = f2bf(w[((size_t)c*SS + s)*25 + tap]);
}

// ---------------- actv (NHWC bf16, zero-padded): relu(gather + bias) ------
// wave-per-cell: 64 lanes x 8 ch (int4), 8 cells per wave
__global__ void k_actv(const int* __restrict__ ids, const unsigned short* __restrict__ Tt,
                       const float* __restrict__ ssb, int4* __restrict__ actv){
  const int t = threadIdx.x, w = t >> 6, lane = t & 63;
  const int cell0 = blockIdx.x*32 + w*8;
  float bias[8];
  #pragma unroll
  for (int i = 0; i < 8; ++i) bias[i] = ssb[lane*8 + i];
  for (int i = 0; i < 8; ++i){
    int cell = cell0 + i;
    int b = cell / PCELLS; int rem = cell - b*PCELLS;
    int r = rem / HP;      int cp = rem - r*HP;
    int4 outv = {0,0,0,0};
    if (r >= 2 && r <= 129 && cp >= 2 && cp <= 129){
      float a[8];
      #pragma unroll
      for (int j = 0; j < 8; ++j) a[j] = bias[j];
      const int* idb = ids + b*PCELLS + (r-2)*HP + (cp-2);
      #pragma unroll
      for (int dy = 0; dy < 5; ++dy){
        #pragma unroll
        for (int dx = 0; dx < 5; ++dx){
          int id = idb[dy*HP + dx];  // wave-uniform -> scalar load
          int4 u = *(const int4*)(Tt + ((size_t)(id*25 + dy*5 + dx))*SS + lane*8);
          a[0] += bflo(u.x); a[1] += bfhi(u.x);
          a[2] += bflo(u.y); a[3] += bfhi(u.y);
          a[4] += bflo(u.z); a[5] += bfhi(u.z);
          a[6] += bflo(u.w); a[7] += bfhi(u.w);
        }
      }
      outv.x = (int)((unsigned)f2bf(fmaxf(a[0],0.f)) | ((unsigned)f2bf(fmaxf(a[1],0.f)) << 16));
      outv.y = (int)((unsigned)f2bf(fmaxf(a[2],0.f)) | ((unsigned)f2bf(fmaxf(a[3],0.f)) << 16));
      outv.z = (int)((unsigned)f2bf(fmaxf(a[4],0.f)) | ((unsigned)f2bf(fmaxf(a[5],0.f)) << 16));
      outv.w = (int)((unsigned)f2bf(fmaxf(a[6],0.f)) | ((unsigned)f2bf(fmaxf(a[7],0.f)) << 16));
    }
    actv[(size_t)cell*64 + lane] = outv;
  }
}

// ---------------- big conv: implicit GEMM, M=256 px, N=256, K=12800 -------
// BK=32, 4 LDS buffers, stage-ahead=3, counted vmcnt(8), 2-phase interleave
__global__ __launch_bounds__(512, 2) void k_conv(
    const unsigned short* __restrict__ actv,   // bf16 [B][132][132][512]
    const unsigned short* __restrict__ W2,     // bf16 [256][12800] (reordered K)
    float* __restrict__ spade)                 // f32  [B][256][128][128]
{
  __shared__ int4 lds4[131072/16];             // 128 KiB: 4 bufs x (A 16K + B 16K)
  char* ldsb = (char*)lds4;
  const int blk = blockIdx.x;
  const int b  = blk >> 6;
  const int y0 = (blk & 63) * 2;
  const int t  = threadIdx.x;
  const int lane = t & 63;
  const int w  = t >> 6;
  const int wr = w >> 2, wc = w & 3;
  const int li = lane & 15, q = lane >> 4;

  // staging constants: source pre-swizzle (rule 21), verified in R1
  const int lsub  = lane >> 2;
  const int s_src = (lane & 3) ^ ((lane >> 3) & 3);
  const bool isA  = (w < 4);
  const char* p0[4];
  int ldsrel[4];
  #pragma unroll
  for (int l = 0; l < 4; ++l){
    int row = (isA ? w : (w - 4)) * 64 + l*16 + lsub;
    if (isA){
      int y = y0 + (row >> 7), x = row & 127;
      p0[l] = (const char*)(actv + (((size_t)b*HP + y)*HP + x)*SS + s_src*8);
    } else {
      p0[l] = (const char*)(W2 + (size_t)row*12800 + s_src*8);
    }
    ldsrel[l] = w*4096 + l*1024 + lane*16;
  }

  auto stage_half = [&](int tt, int h){
    int schunk = tt / 25; int tap = tt - schunk*25;   // K-order: s-chunk major
    int dy = tap / 5, dx = tap - dy*5;
    size_t offA = ((size_t)(dy*HP + dx)*SS + (size_t)schunk*32) * 2;
    size_t off = isA ? offA : (size_t)tt * 64;
    char* base = ldsb + ((tt & 3) * 32768);
    #pragma unroll
    for (int l = h*2; l < h*2 + 2; ++l)
      gld16(p0[l] + off, base + ldsrel[l]);
  };

  f32x4 acc[8][4];
  #pragma unroll
  for (int m = 0; m < 8; ++m)
    #pragma unroll
    for (int n = 0; n < 4; ++n) acc[m][n] = (f32x4){0.f,0.f,0.f,0.f};

  const int swz = (q ^ ((li >> 1) & 3)) * 16;        // read-side swizzle

  auto do_iter = [&](int tt, bool doStage){
    const char* buf  = ldsb + (tt & 3) * 32768;
    const char* arow = buf + (wr*128 + li)*64 + swz;
    const char* brow = buf + 16384 + (wc*64 + li)*64 + swz;
    bf16x8 af[4], bfv[4];
    // ---- phase 1: A rows 0..63 (m0..3) x all n ----
    #pragma unroll
    for (int m = 0; m < 4; ++m) af[m] = *(const bf16x8*)(arow + m*1024);
    #pragma unroll
    for (int n = 0; n < 4; ++n) bfv[n] = *(const bf16x8*)(brow + n*1024);
    if (doStage) stage_half(tt + 3, 0);
    MEMFENCE;
    __builtin_amdgcn_s_barrier();
    asm volatile("s_waitcnt lgkmcnt(0)" ::: "memory");
    __builtin_amdgcn_sched_barrier(0);
    __builtin_amdgcn_s_setprio(1);
    #pragma unroll
    for (int m = 0; m < 4; ++m)
      #pragma unroll
      for (int n = 0; n < 4; ++n)
        acc[m][n] = __builtin_amdgcn_mfma_f32_16x16x32_bf16(af[m], bfv[n], acc[m][n], 0, 0, 0);
    __builtin_amdgcn_s_setprio(0);
    MEMFENCE;
    __builtin_amdgcn_s_barrier();
    MEMFENCE;
    // ---- phase 2: A rows 64..127 (m4..7) x all n ----
    bf16x8 af2[4];
    #pragma unroll
    for (int m = 0; m < 4; ++m) af2[m] = *(const bf16x8*)(arow + (m+4)*1024);
    if (doStage) stage_half(tt + 3, 1);
    MEMFENCE;
    __builtin_amdgcn_s_barrier();
    asm volatile("s_waitcnt lgkmcnt(0)" ::: "memory");
    __builtin_amdgcn_sched_barrier(0);
    __builtin_amdgcn_s_setprio(1);
    #pragma unroll
    for (int m = 0; m < 4; ++m)
      #pragma unroll
      for (int n = 0; n < 4; ++n)
        acc[m+4][n] = __builtin_amdgcn_mfma_f32_16x16x32_bf16(af2[m], bfv[n], acc[m+4][n], 0, 0, 0);
    __builtin_amdgcn_s_setprio(0);
    MEMFENCE;
  };

  // prologue: 3 tiles in flight
  stage_half(0,0); stage_half(0,1);
  stage_half(1,0); stage_half(1,1);
  stage_half(2,0); stage_half(2,1);
  asm volatile("s_waitcnt vmcnt(8)" ::: "memory");   // tile 0 landed
  __builtin_amdgcn_s_barrier();
  MEMFENCE;
  for (int tt = 0; tt < 397; ++tt){
    do_iter(tt, true);
    asm volatile("s_waitcnt vmcnt(8)" ::: "memory"); // tile tt+1 landed
    __builtin_amdgcn_s_barrier();
    MEMFENCE;
  }
  do_iter(397, false);
  asm volatile("s_waitcnt vmcnt(4)" ::: "memory");
  __builtin_amdgcn_s_barrier();
  MEMFENCE;
  do_iter(398, false);
  asm volatile("s_waitcnt vmcnt(0)" ::: "memory");
  __builtin_amdgcn_s_barrier();
  MEMFENCE;
  do_iter(399, false);

  // epilogue: D col = lane&15 -> c', D row = (lane>>4)*4+reg -> pixel
  const int xq4 = (lane >> 4) << 2;
  const int cq  = wc*64 + (lane & 15);
  #pragma unroll
  for (int m = 0; m < 8; ++m){
    int p = wr*128 + m*16 + xq4;
    int y = y0 + (p >> 7), x = p & 127;
    #pragma unroll
    for (int n = 0; n < 4; ++n){
      int cp = cq + n*16;
      float* dst = spade + (((size_t)(b*256 + cp))*HH + y)*WW + x;
      *(f32x4*)dst = acc[m][n];
    }
  }
}

// ---------------- final: avg-path gather + blend + instance-norm apply ----
__global__ void k_final(const float* __restrict__ xin, const int* __restrict__ ids,
                        const float2* __restrict__ G, const float* __restrict__ spade,
                        const float* __restrict__ mean, const float* __restrict__ rstd,
                        const float* __restrict__ cgb, const float* __restrict__ cbb,
                        const float* __restrict__ sgb, const float* __restrict__ sbb,
                        const float* __restrict__ bgam, const float* __restrict__ bbet,
                        float* __restrict__ out){
  const int blk = blockIdx.x;
  const int b = blk >> 7, c = blk & 127;
  const int t = threadIdx.x;
  __shared__ float2 Gl[500];
  for (int i = t; i < 500; i += 256) Gl[i] = G[((size_t)(b*CC + c))*500 + i];
  __syncthreads();
  const float ga = 1.f/(1.f + __expf(-bgam[0]));
  const float ba = 1.f/(1.f + __expf(-bbet[0]));
  const float mn = mean[b*CC + c], rs = rstd[b*CC + c];
  const float cg = cgb[c], cb = cbb[c], sg = sgb[c], sb = sbb[c];
  const float* xp  = xin   + (size_t)(b*CC + c)*NPIX;
  const float* spg = spade + (size_t)(b*256 + c)*NPIX;
  const float* spb = spade + (size_t)(b*256 + c + 128)*NPIX;
  float* op = out + (size_t)(b*CC + c)*NPIX;
  const int* idb = ids + b*PCELLS;
  for (int p = t; p < NPIX; p += 256){
    int y = p >> 7, x = p & 127;
    float ag = 0.f, ab = 0.f;
    #pragma unroll
    for (int dy = 0; dy < 5; ++dy){
      const int* row = idb + (y+dy)*HP + x;
      #pragma unroll
      for (int dx = 0; dx < 5; ++dx){
        int id = row[dx];
        float2 g2 = Gl[id*25 + dy*5 + dx];
        ag += g2.x; ab += g2.y;
      }
    }
    float gf = ga*(ag + cg) + (1.f - ga)*(spg[p] + sg);
    float bf = ba*(ab + cb) + (1.f - ba)*(spb[p] + sb);
    op[p] = (xp[p] - mn)*rs*(1.f + gf) + bf;
  }
}

extern "C" void kernel_launch(void* const* d_in, const int* in_sizes, int n_in,
                              void* d_out, int out_size, void* d_ws, size_t ws_size,
                              hipStream_t stream){
  const float* x    = (const float*)d_in[0];
  const float* seg  = (const float*)d_in[1];
  const float* sty  = (const float*)d_in[2];
  const float* fcw  = (const float*)d_in[3];
  const float* fcb  = (const float*)d_in[4];
  const float* cgw  = (const float*)d_in[5];
  const float* cgb  = (const float*)d_in[6];
  const float* cbw  = (const float*)d_in[7];
  const float* cbb  = (const float*)d_in[8];
  const float* ssw  = (const float*)d_in[9];
  const float* ssb  = (const float*)d_in[10];
  const float* sgw  = (const float*)d_in[11];
  const float* sgb  = (const float*)d_in[12];
  const float* sbw  = (const float*)d_in[13];
  const float* sbb  = (const float*)d_in[14];
  const float* bgam = (const float*)d_in[15];
  const float* bbet = (const float*)d_in[16];
  float* out = (float*)d_out;

  char* ws = (char*)d_ws;
  size_t o = 0;
  auto alloc = [&](size_t n){ size_t r = o; o = (o + n + 255) & ~(size_t)255; return r; };
  float* mean          = (float*)(ws + alloc(512*4));
  float* rstd          = (float*)(ws + alloc(512*4));
  int*   ids           = (int*)  (ws + alloc((size_t)BB*PCELLS*4));
  float* mu            = (float*)(ws + alloc((size_t)BB*LL*SS*4));
  float2* G            = (float2*)(ws + alloc((size_t)BB*CC*500*8));
  unsigned short* Tt   = (unsigned short*)(ws + alloc((size_t)20*25*SS*2));
  unsigned short* W2   = (unsigned short*)(ws + alloc((size_t)256*12800*2));
  unsigned short* actv = (unsigned short*)(ws + alloc((size_t)BB*PCELLS*SS*2));
  float* spade         = (float*)(ws + alloc((size_t)BB*256*NPIX*4));
  // Wt tables alias the spade buffer: consumed by k_gtab BEFORE k_conv writes spade
  float* Wtg = spade;
  float* Wtb = spade + (size_t)128*25*512;
  (void)o; (void)ws_size; (void)in_sizes; (void)n_in; (void)out_size; (void)sty;

  k_stats<<<dim3(512),  dim3(256), 0, stream>>>(x, mean, rstd);
  k_ids  <<<dim3(273),  dim3(256), 0, stream>>>(seg, ids);
  k_fc   <<<dim3(76),   dim3(256), 0, stream>>>(sty, fcw, fcb, mu);
  k_w2t  <<<dim3(6400), dim3(256), 0, stream>>>(cgw, cbw, Wtg, Wtb);
  k_gtab <<<dim3(512),  dim3(256), 0, stream>>>(mu, Wtg, Wtb, G);
  k_ttab <<<dim3(1000), dim3(256), 0, stream>>>(ssw, Tt);
  k_w2   <<<dim3(12800),dim3(256), 0, stream>>>(sgw, sbw, W2);
  k_actv <<<dim3(2178), dim3(256), 0, stream>>>(ids, Tt, ssb, (int4*)actv);
  k_conv <<<dim3(256),  dim3(512), 0, stream>>>(actv, W2, spade);
  k_final<<<dim3(512),  dim3(256), 0, stream>>>(x, ids, G, spade, mean, rstd,
                                                cgb, cbb, sgb, sbb, bgam, bbet, out);
}

// Round 5
// 678.071 us; speedup vs baseline: 1.2619x; 1.1148x over previous
//
#include <hip/hip_runtime.h>
#include <stdint.h>

#define BB 4
#define CC 128
#define HH 128
#define WW 128
#define LL 19
#define SS 512
#define HP 132
#define NPIX (HH*WW)      // 16384
#define PCELLS (HP*HP)    // 17424
#define NCELL (BB*PCELLS) // 69696

typedef float f32x4 __attribute__((ext_vector_type(4)));
typedef __bf16 bf16x8 __attribute__((ext_vector_type(8)));
typedef short short8 __attribute__((ext_vector_type(8)));

#define AS1Q __attribute__((address_space(1)))
#define AS3Q __attribute__((address_space(3)))
#define MEMFENCE asm volatile("" ::: "memory")

__device__ __forceinline__ void gld16(const void* g, void* l){
  __builtin_amdgcn_global_load_lds((const AS1Q void*)g, (AS3Q void*)l, 16, 0, 0);
}

__device__ inline unsigned short f2bf(float v){
  unsigned u = __float_as_uint(v);
  return (unsigned short)((u + 0x7fffu + ((u >> 16) & 1u)) >> 16);
}
__device__ inline float bflo(unsigned u){ return __uint_as_float(u << 16); }
__device__ inline float bfhi(unsigned u){ return __uint_as_float(u & 0xffff0000u); }

// ---------------- instance-norm stats ----------------
__global__ void k_stats(const float* __restrict__ x, float* __restrict__ mean,
                        float* __restrict__ rstd){
  const int bc = blockIdx.x;
  const int t = threadIdx.x;
  const int w = t >> 6, lane = t & 63;
  const float4* xv = (const float4*)(x + (size_t)bc * NPIX);
  float s = 0.f, q = 0.f;
  for (int i = t; i < NPIX/4; i += 256){
    float4 v = xv[i];
    s += v.x + v.y + v.z + v.w;
    q += v.x*v.x + v.y*v.y + v.z*v.z + v.w*v.w;
  }
  #pragma unroll
  for (int off = 32; off; off >>= 1){ s += __shfl_down(s, off); q += __shfl_down(q, off); }
  __shared__ float ls[4], lq[4];
  if (lane == 0){ ls[w] = s; lq[w] = q; }
  __syncthreads();
  if (t == 0){
    float S = ls[0]+ls[1]+ls[2]+ls[3];
    float Q = lq[0]+lq[1]+lq[2]+lq[3];
    float mn = S * (1.f/16384.f);
    float var = Q * (1.f/16384.f) - mn*mn;
    mean[bc] = mn;
    rstd[bc] = rsqrtf(var + 1e-5f);
  }
}

// ---------------- padded label ids (border sentinel = 19) ----------------
__global__ void k_ids(const float* __restrict__ seg, int* __restrict__ ids){
  int idx = blockIdx.x*256 + threadIdx.x;
  if (idx >= NCELL) return;
  int b = idx / PCELLS; int rem = idx - b*PCELLS;
  int r = rem / HP;     int cp = rem - r*HP;
  int id = LL;
  if (r >= 2 && r <= 129 && cp >= 2 && cp <= 129){
    int p = (r-2)*WW + (cp-2);
    const float* sp = seg + (size_t)b*LL*NPIX + p;
    id = 0;
    for (int j = 0; j < LL; ++j){
      if (sp[(size_t)j*NPIX] > 0.5f){ id = j; break; }
    }
  }
  ids[idx] = id;
}

// ---------------- style FC: 76 blocks = (j, e-quarter); fcw read once -----
__global__ void k_fc(const float* __restrict__ style, const float* __restrict__ fcw,
                     const float* __restrict__ fcb, float* __restrict__ mu){
  const int j = blockIdx.x >> 2, part = blockIdx.x & 3;
  const int t = threadIdx.x, w = t >> 6, lane = t & 63;
  __shared__ float s_s[4][SS];
  for (int i = t; i < 4*SS; i += 256){
    int b = i >> 9, e = i & 511;
    s_s[b][e] = style[(size_t)(b*LL + j)*SS + e];
  }
  __syncthreads();
  for (int e = part*128 + w; e < part*128 + 128; e += 4){
    const float* row = fcw + ((size_t)(j*SS + e))*SS;
    float a0=0.f, a1=0.f, a2=0.f, a3=0.f;
    #pragma unroll
    for (int i = 0; i < 8; ++i){
      int d = lane + i*64; float rv = row[d];
      a0 += s_s[0][d]*rv; a1 += s_s[1][d]*rv;
      a2 += s_s[2][d]*rv; a3 += s_s[3][d]*rv;
    }
    #pragma unroll
    for (int off = 32; off; off >>= 1){
      a0 += __shfl_down(a0,off); a1 += __shfl_down(a1,off);
      a2 += __shfl_down(a2,off); a3 += __shfl_down(a3,off);
    }
    if (lane == 0){
      float fb = fcb[j*SS + e];
      mu[(size_t)(0*LL+j)*SS + e] = fmaxf(a0+fb, 0.f);
      mu[(size_t)(1*LL+j)*SS + e] = fmaxf(a1+fb, 0.f);
      mu[(size_t)(2*LL+j)*SS + e] = fmaxf(a2+fb, 0.f);
      mu[(size_t)(3*LL+j)*SS + e] = fmaxf(a3+fb, 0.f);
    }
  }
}

// ---------------- fused prep: w2t (6400) + ttab (1000) + w2 (12800) -------
__global__ void k_prep(const float* __restrict__ cgw, const float* __restrict__ cbw,
                       float* __restrict__ Wtg, float* __restrict__ Wtb,
                       const float* __restrict__ ssw, unsigned short* __restrict__ Tt,
                       const float* __restrict__ sgw, const float* __restrict__ sbw,
                       unsigned short* __restrict__ W2){
  int blk = blockIdx.x;
  if (blk < 6400){
    int idx = blk*256 + threadIdx.x;           // 128*25*512
    int e = idx & 511; int rest = idx >> 9;
    int c = rest / 25, d = rest - (rest/25)*25;
    size_t src = ((size_t)c*SS + e)*25 + d;
    Wtg[idx] = cgw[src];
    Wtb[idx] = cbw[src];
  } else if (blk < 7400){
    int idx = (blk-6400)*256 + threadIdx.x;    // 20*25*512
    if (idx < 20*25*SS){
      int s = idx & 511; int rest = idx >> 9;
      int j = rest / 25, d = rest - (rest/25)*25;
      float v = 0.f;
      if (j < LL) v = ssw[((size_t)s*LL + j)*25 + d];
      Tt[idx] = f2bf(v);
    }
  } else {
    int idx = (blk-7400)*256 + threadIdx.x;    // 256*12800, k: s-chunk major
    int cpr = idx / 12800; int k = idx - cpr*12800;
    int schunk = k / 800; int r800 = k - schunk*800;
    int tap = r800 >> 5;  int s_in = r800 & 31;
    int s = schunk*32 + s_in;
    const float* w = (cpr < 128) ? sgw : sbw;
    int c = cpr & 127;
    W2[idx] = f2bf(w[((size_t)c*SS + s)*25 + tap]);
  }
}

// ---------------- G table: wave-per-output coalesced dot ------------------
__global__ void k_gtab(const float* __restrict__ mu, const float* __restrict__ Wtg,
                       const float* __restrict__ Wtb, float2* __restrict__ G){
  const int blk = blockIdx.x;
  const int b = blk >> 7, c = blk & 127;
  const int t = threadIdx.x, w = t >> 6, lane = t & 63;
  __shared__ float mu_s[LL*SS];
  for (int i = t; i < LL*SS; i += 256) mu_s[i] = mu[(size_t)b*LL*SS + i];
  __syncthreads();
  for (int i = 0; i < 125; ++i){
    int o = i*4 + w;
    int j = o / 25, d = o - (o/25)*25;
    float ag = 0.f, ab = 0.f;
    if (j < LL){
      const float4* wg4 = (const float4*)(Wtg + ((size_t)c*25 + d)*SS);
      const float4* wb4 = (const float4*)(Wtb + ((size_t)c*25 + d)*SS);
      const float4* m4p = (const float4*)(mu_s + j*SS);
      #pragma unroll
      for (int rp = 0; rp < 2; ++rp){
        int e4 = rp*64 + lane;
        float4 m4 = m4p[e4];
        float4 wv = wg4[e4];
        ag += m4.x*wv.x + m4.y*wv.y + m4.z*wv.z + m4.w*wv.w;
        float4 wv2 = wb4[e4];
        ab += m4.x*wv2.x + m4.y*wv2.y + m4.z*wv2.z + m4.w*wv2.w;
      }
      #pragma unroll
      for (int off = 32; off; off >>= 1){ ag += __shfl_down(ag, off); ab += __shfl_down(ab, off); }
    }
    if (lane == 0) G[((size_t)(b*CC + c))*500 + o] = make_float2(ag, ab);
  }
}

// ---------------- actv: Tt slice cached in LDS (500 x 128ch, 272B stride) -
__global__ __launch_bounds__(256) void k_actv(
    const int* __restrict__ ids, const unsigned short* __restrict__ Tt,
    const float* __restrict__ ssb, int4* __restrict__ actv){
  __shared__ unsigned short Tl[500*136];       // 136000 B
  const int t = threadIdx.x, w = t >> 6, lane = t & 63;
  const int cs  = blockIdx.x & 3;              // channel slice (128 ch)
  const int cg0 = blockIdx.x >> 2;             // cell group (128 cells)
  for (int i = t; i < 8000; i += 256){         // 500 rows x 16 int4
    int row = i >> 4, sub = i & 15;
    int4 v = *(const int4*)(Tt + (size_t)row*512 + cs*128 + sub*8);
    *(int4*)(Tl + row*136 + sub*8) = v;
  }
  __syncthreads();
  const int chsub = lane & 15;                 // 8-ch group within slice
  const int csub  = lane >> 4;                 // cell within 4-pack
  float bias[8];
  #pragma unroll
  for (int i = 0; i < 8; ++i) bias[i] = ssb[cs*128 + chsub*8 + i];
  for (int it = 0; it < 8; ++it){
    int cell = cg0*128 + it*16 + w*4 + csub;
    if (cell >= NCELL) break;
    int b = cell / PCELLS; int rem = cell - b*PCELLS;
    int r = rem / HP;      int cp = rem - r*HP;
    int4 outv = {0,0,0,0};
    if (r >= 2 && r <= 129 && cp >= 2 && cp <= 129){
      float a[8];
      #pragma unroll
      for (int i = 0; i < 8; ++i) a[i] = bias[i];
      const int* idb = ids + b*PCELLS + (r-2)*HP + (cp-2);
      int idw[25];
      #pragma unroll
      for (int dy = 0; dy < 5; ++dy)
        #pragma unroll
        for (int dx = 0; dx < 5; ++dx) idw[dy*5+dx] = idb[dy*HP + dx];
      #pragma unroll
      for (int tap = 0; tap < 25; ++tap){
        int4 u = *(const int4*)(Tl + (idw[tap]*25 + tap)*136 + chsub*8);
        a[0] += bflo(u.x); a[1] += bfhi(u.x);
        a[2] += bflo(u.y); a[3] += bfhi(u.y);
        a[4] += bflo(u.z); a[5] += bfhi(u.z);
        a[6] += bflo(u.w); a[7] += bfhi(u.w);
      }
      outv.x = (int)((unsigned)f2bf(fmaxf(a[0],0.f)) | ((unsigned)f2bf(fmaxf(a[1],0.f)) << 16));
      outv.y = (int)((unsigned)f2bf(fmaxf(a[2],0.f)) | ((unsigned)f2bf(fmaxf(a[3],0.f)) << 16));
      outv.z = (int)((unsigned)f2bf(fmaxf(a[4],0.f)) | ((unsigned)f2bf(fmaxf(a[5],0.f)) << 16));
      outv.w = (int)((unsigned)f2bf(fmaxf(a[6],0.f)) | ((unsigned)f2bf(fmaxf(a[7],0.f)) << 16));
    }
    // FIX (R3 bug): layout is 64 int4/cell; slice cs occupies [cs*16, cs*16+16)
    actv[(size_t)cell*64 + cs*16 + chsub] = outv;
  }
}

// ---------------- big conv: m201-style 4-phase/BK64 schedule --------------
__global__ __launch_bounds__(512, 2) void k_conv(
    const unsigned short* __restrict__ actv,   // bf16 [B][132][132][512]
    const unsigned short* __restrict__ W2,     // bf16 [256][12800] (reordered K)
    unsigned short* __restrict__ spade)        // bf16 [B][256][128][128]
{
  __shared__ int4 lds4[131072/16];             // 128 KiB: 4 bufs x (A 16K + B 16K)
  char* ldsb = (char*)lds4;
  const int blk = blockIdx.x;
  const int b  = blk >> 6;
  const int y0 = (blk & 63) * 2;
  const int t  = threadIdx.x;
  const int lane = t & 63;
  const int w  = t >> 6;
  const int wr = w >> 2, wc = w & 3;
  const int li = lane & 15, q = lane >> 4;

  // staging: source pre-swizzle (verified R1/R2)
  const int lsub  = lane >> 2;
  const int s_src = (lane & 3) ^ ((lane >> 3) & 3);
  const bool isA  = (w < 4);
  const char* p0[4];
  int ldsrel[4];
  #pragma unroll
  for (int l = 0; l < 4; ++l){
    int row = (isA ? w : (w - 4)) * 64 + l*16 + lsub;
    if (isA){
      int y = y0 + (row >> 7), x = row & 127;
      p0[l] = (const char*)(actv + (((size_t)b*HP + y)*HP + x)*SS + s_src*8);
    } else {
      p0[l] = (const char*)(W2 + (size_t)row*12800 + s_src*8);
    }
    ldsrel[l] = w*4096 + l*1024 + lane*16;
  }

  auto stage_tt = [&](int tt){               // 4 loads/thread
    int schunk = tt / 25; int tap = tt - schunk*25;
    int dy = tap / 5, dx = tap - dy*5;
    size_t offA = ((size_t)(dy*HP + dx)*SS + (size_t)schunk*32) * 2;
    size_t off = isA ? offA : (size_t)tt * 64;
    char* base = ldsb + ((tt & 3) * 32768);
    #pragma unroll
    for (int l = 0; l < 4; ++l)
      gld16(p0[l] + off, base + ldsrel[l]);
  };

  f32x4 acc[8][4];
  #pragma unroll
  for (int m = 0; m < 8; ++m)
    #pragma unroll
    for (int n = 0; n < 4; ++n) acc[m][n] = (f32x4){0.f,0.f,0.f,0.f};

  const int swz = (q ^ ((li >> 1) & 3)) * 16;

  // one BK=64 iteration = 4 phases; reads 8/4/8/4; 16 MFMA each
  auto do_iter64 = [&](int t2, bool st1, bool st3, int vmclose){
    const char* bufe = ldsb + (( 2*t2   ) & 3) * 32768;   // kk0
    const char* bufo = ldsb + ((2*t2 + 1) & 3) * 32768;   // kk1
    const char* arow0 = bufe + (wr*128 + li)*64 + swz;
    const char* brow0 = bufe + 16384 + (wc*64 + li)*64 + swz;
    const char* arow1 = bufo + (wr*128 + li)*64 + swz;
    const char* brow1 = bufo + 16384 + (wc*64 + li)*64 + swz;
    bf16x8 af[4], bfv[4];
    // ---- P1: A[m0-3,kk0] + B[*,kk0]; stage 2t2+3; MFMA acc[0-3] ----
    #pragma unroll
    for (int m = 0; m < 4; ++m) af[m] = *(const bf16x8*)(arow0 + m*1024);
    #pragma unroll
    for (int n = 0; n < 4; ++n) bfv[n] = *(const bf16x8*)(brow0 + n*1024);
    if (st1) stage_tt(2*t2 + 3);
    MEMFENCE; __builtin_amdgcn_s_barrier();
    asm volatile("s_waitcnt lgkmcnt(0)" ::: "memory");
    __builtin_amdgcn_sched_barrier(0);
    __builtin_amdgcn_s_setprio(1);
    #pragma unroll
    for (int m = 0; m < 4; ++m)
      #pragma unroll
      for (int n = 0; n < 4; ++n)
        acc[m][n] = __builtin_amdgcn_mfma_f32_16x16x32_bf16(af[m], bfv[n], acc[m][n], 0, 0, 0);
    __builtin_amdgcn_s_setprio(0);
    MEMFENCE;
    // ---- P2: A[m4-7,kk0]; MFMA acc[4-7] ----
    #pragma unroll
    for (int m = 0; m < 4; ++m) af[m] = *(const bf16x8*)(arow0 + (m+4)*1024);
    MEMFENCE; __builtin_amdgcn_s_barrier();
    asm volatile("s_waitcnt lgkmcnt(0)" ::: "memory");
    __builtin_amdgcn_sched_barrier(0);
    __builtin_amdgcn_s_setprio(1);
    #pragma unroll
    for (int m = 0; m < 4; ++m)
      #pragma unroll
      for (int n = 0; n < 4; ++n)
        acc[m+4][n] = __builtin_amdgcn_mfma_f32_16x16x32_bf16(af[m], bfv[n], acc[m+4][n], 0, 0, 0);
    __builtin_amdgcn_s_setprio(0);
    MEMFENCE; __builtin_amdgcn_s_barrier(); MEMFENCE;  // P3 stages buf read in P1/P2
    // ---- P3: A[m0-3,kk1] + B[*,kk1]; stage 2t2+4; MFMA acc[0-3] ----
    #pragma unroll
    for (int m = 0; m < 4; ++m) af[m] = *(const bf16x8*)(arow1 + m*1024);
    #pragma unroll
    for (int n = 0; n < 4; ++n) bfv[n] = *(const bf16x8*)(brow1 + n*1024);
    if (st3) stage_tt(2*t2 + 4);
    MEMFENCE; __builtin_amdgcn_s_barrier();
    asm volatile("s_waitcnt lgkmcnt(0)" ::: "memory");
    __builtin_amdgcn_sched_barrier(0);
    __builtin_amdgcn_s_setprio(1);
    #pragma unroll
    for (int m = 0; m < 4; ++m)
      #pragma unroll
      for (int n = 0; n < 4; ++n)
        acc[m][n] = __builtin_amdgcn_mfma_f32_16x16x32_bf16(af[m], bfv[n], acc[m][n], 0, 0, 0);
    __builtin_amdgcn_s_setprio(0);
    MEMFENCE;
    // ---- P4: A[m4-7,kk1]; MFMA acc[4-7]; close: counted vmcnt + bar ----
    #pragma unroll
    for (int m = 0; m < 4; ++m) af[m] = *(const bf16x8*)(arow1 + (m+4)*1024);
    MEMFENCE; __builtin_amdgcn_s_barrier();
    asm volatile("s_waitcnt lgkmcnt(0)" ::: "memory");
    __builtin_amdgcn_sched_barrier(0);
    __builtin_amdgcn_s_setprio(1);
    #pragma unroll
    for (int m = 0; m < 4; ++m)
      #pragma unroll
      for (int n = 0; n < 4; ++n)
        acc[m+4][n] = __builtin_amdgcn_mfma_f32_16x16x32_bf16(af[m], bfv[n], acc[m+4][n], 0, 0, 0);
    __builtin_amdgcn_s_setprio(0);
    MEMFENCE;
    if (vmclose == 4)      asm volatile("s_waitcnt vmcnt(4)" ::: "memory");
    else if (vmclose == 0) asm volatile("s_waitcnt vmcnt(0)" ::: "memory");
    if (vmclose >= 0){ __builtin_amdgcn_s_barrier(); MEMFENCE; }
  };

  // prologue: 3 BK32 tiles in flight
  stage_tt(0); stage_tt(1); stage_tt(2);
  asm volatile("s_waitcnt vmcnt(4)" ::: "memory");   // tts 0,1 landed
  __builtin_amdgcn_s_barrier();
  MEMFENCE;
  for (int t2 = 0; t2 < 198; ++t2) do_iter64(t2, true, true, 4);
  do_iter64(198, true, false, 0);
  do_iter64(199, false, false, -1);

  // epilogue: bf16 pack; D col=lane&15 -> c', D row -> pixel (4 contig)
  const int xq4 = (lane >> 4) << 2;
  const int cq  = wc*64 + (lane & 15);
  #pragma unroll
  for (int m = 0; m < 8; ++m){
    int p = wr*128 + m*16 + xq4;
    int y = y0 + (p >> 7), x = p & 127;
    #pragma unroll
    for (int n = 0; n < 4; ++n){
      int cp = cq + n*16;
      f32x4 v = acc[m][n];
      uint2 pk;
      pk.x = (unsigned)f2bf(v.x) | ((unsigned)f2bf(v.y) << 16);
      pk.y = (unsigned)f2bf(v.z) | ((unsigned)f2bf(v.w) << 16);
      *(uint2*)(spade + (((size_t)(b*256 + cp))*HH + y)*WW + x) = pk;
    }
  }
}

// ---------------- final: paired-pixel gather + blend + IN apply -----------
__global__ void k_final(const float* __restrict__ xin, const int* __restrict__ ids,
                        const float2* __restrict__ G, const unsigned short* __restrict__ spade,
                        const float* __restrict__ mean, const float* __restrict__ rstd,
                        const float* __restrict__ cgb, const float* __restrict__ cbb,
                        const float* __restrict__ sgb, const float* __restrict__ sbb,
                        const float* __restrict__ bgam, const float* __restrict__ bbet,
                        float* __restrict__ out){
  const int blk = blockIdx.x;
  const int b = blk >> 7, c = blk & 127;
  const int t = threadIdx.x;
  __shared__ float2 Gl2[500];                  // [tap][id] transposed
  for (int i = t; i < 500; i += 256){
    int j = i / 25, d = i - (i/25)*25;
    Gl2[d*20 + j] = G[((size_t)(b*CC + c))*500 + i];
  }
  __syncthreads();
  const float ga = 1.f/(1.f + __expf(-bgam[0]));
  const float ba = 1.f/(1.f + __expf(-bbet[0]));
  const float mn = mean[b*CC + c], rs = rstd[b*CC + c];
  const float cg = cgb[c], cb = cbb[c], sg = sgb[c], sb = sbb[c];
  const float* xp  = xin + (size_t)(b*CC + c)*NPIX;
  const unsigned short* spg = spade + (size_t)(b*256 + c)*NPIX;
  const unsigned short* spb = spade + (size_t)(b*256 + c + 128)*NPIX;
  float* op = out + (size_t)(b*CC + c)*NPIX;
  const int* idb = ids + b*PCELLS;
  for (int p2 = t; p2 < NPIX/2; p2 += 256){
    int p = p2*2;
    int y = p >> 7, x = p & 127;
    float ag0=0.f, ab0=0.f, ag1=0.f, ab1=0.f;
    #pragma unroll
    for (int dy = 0; dy < 5; ++dy){
      const int* row = idb + (y+dy)*HP + x;
      int idv[6];
      #pragma unroll
      for (int k = 0; k < 6; ++k) idv[k] = row[k];
      #pragma unroll
      for (int dx = 0; dx < 5; ++dx){
        float2 g0 = Gl2[(dy*5+dx)*20 + idv[dx]];
        float2 g1 = Gl2[(dy*5+dx)*20 + idv[dx+1]];
        ag0 += g0.x; ab0 += g0.y;
        ag1 += g1.x; ab1 += g1.y;
      }
    }
    unsigned sg2 = *(const unsigned*)(spg + p);
    unsigned sb2 = *(const unsigned*)(spb + p);
    float2 xv = *(const float2*)(xp + p);
    float gf0 = ga*(ag0 + cg) + (1.f - ga)*(bflo(sg2) + sg);
    float bf0 = ba*(ab0 + cb) + (1.f - ba)*(bflo(sb2) + sb);
    float gf1 = ga*(ag1 + cg) + (1.f - ga)*(bfhi(sg2) + sg);
    float bf1 = ba*(ab1 + cb) + (1.f - ba)*(bfhi(sb2) + sb);
    float2 ov;
    ov.x = (xv.x - mn)*rs*(1.f + gf0) + bf0;
    ov.y = (xv.y - mn)*rs*(1.f + gf1) + bf1;
    *(float2*)(op + p) = ov;
  }
}

extern "C" void kernel_launch(void* const* d_in, const int* in_sizes, int n_in,
                              void* d_out, int out_size, void* d_ws, size_t ws_size,
                              hipStream_t stream){
  const float* x    = (const float*)d_in[0];
  const float* seg  = (const float*)d_in[1];
  const float* sty  = (const float*)d_in[2];
  const float* fcw  = (const float*)d_in[3];
  const float* fcb  = (const float*)d_in[4];
  const float* cgw  = (const float*)d_in[5];
  const float* cgb  = (const float*)d_in[6];
  const float* cbw  = (const float*)d_in[7];
  const float* cbb  = (const float*)d_in[8];
  const float* ssw  = (const float*)d_in[9];
  const float* ssb  = (const float*)d_in[10];
  const float* sgw  = (const float*)d_in[11];
  const float* sgb  = (const float*)d_in[12];
  const float* sbw  = (const float*)d_in[13];
  const float* sbb  = (const float*)d_in[14];
  const float* bgam = (const float*)d_in[15];
  const float* bbet = (const float*)d_in[16];
  float* out = (float*)d_out;

  char* ws = (char*)d_ws;
  size_t o = 0;
  auto alloc = [&](size_t n){ size_t r = o; o = (o + n + 255) & ~(size_t)255; return r; };
  float* mean          = (float*)(ws + alloc(512*4));
  float* rstd          = (float*)(ws + alloc(512*4));
  int*   ids           = (int*)  (ws + alloc((size_t)NCELL*4));
  float* mu            = (float*)(ws + alloc((size_t)BB*LL*SS*4));
  float2* G            = (float2*)(ws + alloc((size_t)BB*CC*500*8));
  unsigned short* Tt   = (unsigned short*)(ws + alloc((size_t)20*25*SS*2));
  unsigned short* W2   = (unsigned short*)(ws + alloc((size_t)256*12800*2));
  unsigned short* actv = (unsigned short*)(ws + alloc((size_t)NCELL*SS*2));
  unsigned short* spade= (unsigned short*)(ws + alloc((size_t)BB*256*NPIX*2 < (size_t)2*128*25*512*4
                                                      ? (size_t)2*128*25*512*4
                                                      : (size_t)BB*256*NPIX*2));
  // Wt tables alias spade region (consumed by k_gtab before k_conv writes it)
  float* Wtg = (float*)spade;
  float* Wtb = (float*)spade + (size_t)128*25*512;
  (void)o; (void)ws_size; (void)in_sizes; (void)n_in; (void)out_size; (void)sty;

  k_stats<<<dim3(512),  dim3(256), 0, stream>>>(x, mean, rstd);
  k_ids  <<<dim3(273),  dim3(256), 0, stream>>>(seg, ids);
  k_fc   <<<dim3(76),   dim3(256), 0, stream>>>(sty, fcw, fcb, mu);
  k_prep <<<dim3(20200),dim3(256), 0, stream>>>(cgw, cbw, Wtg, Wtb, ssw, Tt, sgw, sbw, W2);
  k_gtab <<<dim3(512),  dim3(256), 0, stream>>>(mu, Wtg, Wtb, G);
  k_actv <<<dim3(2180), dim3(256), 0, stream>>>(ids, Tt, ssb, (int4*)actv);
  k_conv <<<dim3(256),  dim3(512), 0, stream>>>(actv, W2, spade);
  k_final<<<dim3(512),  dim3(256), 0, stream>>>(x, ids, G, spade, mean, rstd,
                                                cgb, cbb, sgb, sbb, bgam, bbet, out);
}